// Round 2
// baseline (578.742 us; speedup 1.0000x reference)
//
#include <hip/hip_runtime.h>
#include <hip/hip_bf16.h>

// SO3Linear: out[b,m,o] = sum_i x[b,m,i] * (W[l(m),o,i] - 1/sqrt(128)), bias on m=0.
// bf16 MFMA 16x16x32, fp32 accumulate. Grid (128 batch-chunks, 25 m).
// R1 -> R2: epilogue now transposes acc through LDS so global stores are
// full-line dwordx4 (R1 had 1.8x write amplification from scattered 64B
// half-line dword stores, and 32 outstanding scalar stores per iter
// serialized the loop via vmcnt drain).

#define BATCH 16384
#define NUM_M 25
#define NF 128
#define BB 128                      // batch-chunks per m
#define ROWS_PER_BLOCK (BATCH / BB) // 128
#define TILE_ROWS 64                // 4 waves x 16 rows
#define PAD 132                     // LDS row stride in floats (16B-aligned, conflict-free)

typedef __attribute__((ext_vector_type(8))) short short8;   // 8 bf16 (4 VGPRs)
typedef __attribute__((ext_vector_type(4))) float floatx4;  // MFMA C/D + vec IO

// fp32 -> bf16, round-to-nearest-even (inputs finite)
__device__ inline short f2bf(float f) {
    union { float f; unsigned u; } v;
    v.f = f;
    unsigned r = v.u + 0x7fffu + ((v.u >> 16) & 1u);
    return (short)(r >> 16);
}

__global__ __launch_bounds__(256, 2)
void so3_mfma_kernel(const float* __restrict__ x,
                     const float* __restrict__ w,
                     const float* __restrict__ bias,
                     float* __restrict__ out) {
    __shared__ float lds[4 * 16 * PAD]; // 33792 B, one 16xPAD tile per wave

    const int m = blockIdx.y;
    const int l = (m >= 16) ? 4 : (m >= 9) ? 3 : (m >= 4) ? 2 : (m >= 1) ? 1 : 0;
    const int wave = threadIdx.x >> 6;
    const int lane = threadIdx.x & 63;
    const int q    = lane >> 4;   // 0..3
    const int n16  = lane & 15;   // 0..15
    const int h    = lane >> 5;   // 0..1  (epilogue row-half)
    const int c    = lane & 31;   // 0..31 (epilogue col chunk, 16B each)
    const float bound = 0.08838834764831843f; // 1/sqrt(128)

    // ---- B fragments (centered weights), register-resident for whole block ----
    // B lane layout: col n = lane&15, k = q*8 + j (j=0..7) per 32-wide k-chunk.
    short8 bfrag[8][4];
    {
        const float* wl = w + l * NF * NF;
        #pragma unroll
        for (int nt = 0; nt < 8; ++nt) {
            const int o = nt * 16 + n16;
            #pragma unroll
            for (int kc = 0; kc < 4; ++kc) {
                const int k = kc * 32 + q * 8;
                const floatx4* p = (const floatx4*)(wl + o * NF + k);
                floatx4 w0 = p[0], w1 = p[1];
                short8 f;
                f[0] = f2bf(w0[0] - bound); f[1] = f2bf(w0[1] - bound);
                f[2] = f2bf(w0[2] - bound); f[3] = f2bf(w0[3] - bound);
                f[4] = f2bf(w1[0] - bound); f[5] = f2bf(w1[1] - bound);
                f[6] = f2bf(w1[2] - bound); f[7] = f2bf(w1[3] - bound);
                bfrag[nt][kc] = f;
            }
        }
    }

    // bias applies only to m==0 rows (block-uniform)
    float bvals[8];
    #pragma unroll
    for (int nt = 0; nt < 8; ++nt)
        bvals[nt] = (m == 0) ? bias[nt * 16 + n16] : 0.0f;

    const int b0 = blockIdx.x * ROWS_PER_BLOCK;
    float* lw = lds + wave * 16 * PAD;

    for (int it = 0; it < ROWS_PER_BLOCK / TILE_ROWS; ++it) {
        const int rowb = b0 + it * TILE_ROWS + wave * 16; // batch base of 16-row tile

        // ---- A fragments: lane holds x[rowb + n16][kc*32 + q*8 .. +8] ----
        short8 a[4];
        {
            const float* xr = x + ((rowb + n16) * NUM_M + m) * NF;
            #pragma unroll
            for (int kc = 0; kc < 4; ++kc) {
                const floatx4* p = (const floatx4*)(xr + kc * 32 + q * 8);
                floatx4 x0 = p[0], x1 = p[1];
                short8 f;
                f[0] = f2bf(x0[0]); f[1] = f2bf(x0[1]);
                f[2] = f2bf(x0[2]); f[3] = f2bf(x0[3]);
                f[4] = f2bf(x1[0]); f[5] = f2bf(x1[1]);
                f[6] = f2bf(x1[2]); f[7] = f2bf(x1[3]);
                a[kc] = f;
            }
        }

        // ---- MFMA: 8 independent acc chains, 4 k-steps each ----
        floatx4 acc[8] = {};
        #pragma unroll
        for (int nt = 0; nt < 8; ++nt) {
            #pragma unroll
            for (int kc = 0; kc < 4; ++kc) {
                acc[nt] = __builtin_amdgcn_mfma_f32_16x16x32_bf16(
                    a[kc], bfrag[nt][kc], acc[nt], 0, 0, 0);
            }
        }

        // ---- epilogue: transpose through per-wave LDS tile ----
        // WAR fence vs previous iteration's ds_reads (same-wave lockstep, in-order LDS)
        __asm__ __volatile__("s_waitcnt lgkmcnt(0)" ::: "memory");
        // C/D layout: col = n16, row = q*4 + r. Banks: (16q + 4r + 16nt + n16)%32
        // -> each 32-lane phase conflict-free.
        #pragma unroll
        for (int nt = 0; nt < 8; ++nt) {
            #pragma unroll
            for (int r = 0; r < 4; ++r) {
                lw[(q * 4 + r) * PAD + nt * 16 + n16] = acc[nt][r] + bvals[nt];
            }
        }
        __asm__ __volatile__("s_waitcnt lgkmcnt(0)" ::: "memory");
        // Read row-major: lane (h,c) reads 16B of row r2*2+h -> 8-lane phases
        // contiguous = conflict-free. Store dwordx4: 2 full 512B rows per instr.
        #pragma unroll
        for (int r2 = 0; r2 < 8; ++r2) {
            const int row = r2 * 2 + h;
            floatx4 v = *(const floatx4*)(lw + row * PAD + c * 4);
            *(floatx4*)(out + ((rowb + row) * NUM_M + m) * NF + c * 4) = v;
        }
    }
}

extern "C" void kernel_launch(void* const* d_in, const int* in_sizes, int n_in,
                              void* d_out, int out_size, void* d_ws, size_t ws_size,
                              hipStream_t stream) {
    const float* x    = (const float*)d_in[0]; // [16384, 25, 128]
    const float* w    = (const float*)d_in[1]; // [5, 128, 128]
    const float* bias = (const float*)d_in[2]; // [128]
    float* out = (float*)d_out;                // [16384, 25, 128]

    dim3 grid(BB, NUM_M);
    dim3 block(256);
    so3_mfma_kernel<<<grid, block, 0, stream>>>(x, w, bias, out);
}